// Round 5
// baseline (513.255 us; speedup 1.0000x reference)
//
#include <hip/hip_runtime.h>
#include <hip/hip_bf16.h>

// Problem constants
constexpr int kB  = 4;
constexpr int kS  = 1024;
constexpr int kD  = 2048;
constexpr int kH  = 32;
constexpr int kKV = 8;
constexpr int kHD = 64;

constexpr float kNegBig = -30000.0f;   // finite sentinel: no inf/overflow paths
constexpr float kC = 0.125f * 1.44269504f;  // 1/sqrt(HD) folded into exp2
constexpr float kDeferThr = 40.0f;     // defer-max raw threshold: P <= 2^(40*kC) ~ 147

typedef __attribute__((ext_vector_type(8))) short short8;   // 8 bf16 (4 VGPRs)
typedef __attribute__((ext_vector_type(4))) float floatx4;  // MFMA C/D

static __device__ __forceinline__ float bf2f(short v) {
    unsigned int u = ((unsigned int)(unsigned short)v) << 16;
    return __builtin_bit_cast(float, u);
}
static __device__ __forceinline__ short f2bf(float f) {
    unsigned int u = __builtin_bit_cast(unsigned int, f);
    unsigned int lsb = (u >> 16) & 1u;
    u += 0x7fffu + lsb;                       // round-to-nearest-even
    return (short)(u >> 16);
}
// Cheap pack for P >= 0: round-half-up (bias ~2^-9 relative, harmless).
static __device__ __forceinline__ short f2bf_fast(float f) {
    unsigned int u = __builtin_bit_cast(unsigned int, f);
    return (short)((u + 0x8000u) >> 16);
}

// Async global->LDS, 16 B per lane. LDS dest is wave-uniform base + lane*16.
static __device__ __forceinline__ void load_lds16(const short* g, short* l) {
    __builtin_amdgcn_global_load_lds(
        (const __attribute__((address_space(1))) unsigned int*)g,
        (__attribute__((address_space(3))) unsigned int*)l, 16, 0, 0);
}

// fp32 -> bf16, vectorized x4. n4 = element_count/4.
__global__ void cast_f2b(const float* __restrict__ in, short* __restrict__ outp, int n4) {
    int gid = blockIdx.x * blockDim.x + threadIdx.x;
    if (gid >= n4) return;
    float4 v = ((const float4*)in)[gid];
    short4 o;
    o.x = f2bf(v.x); o.y = f2bf(v.y); o.z = f2bf(v.z); o.w = f2bf(v.w);
    ((short4*)outp)[gid] = o;
}

// C[M,N] = A[M,K] * B[N,K]^T, bf16 in, fp32 acc, OT out (bf16 short or fp32).
// m97 structure: 128x128 tile, BK=32, global_load_lds width=16 staging,
// 2-barrier K-loop, ds_read_b128 fragments. Block = 4 waves in 2x2.
// XCD-aware bijective blockIdx swizzle (T1); requires nwg % 8 == 0 (guarded).
// ROPE: 0 = none, 1 = all columns (Q proj), 2 = KV mode: cols < 512 get RoPE
// (K half), cols >= 512 (V half) are stored TRANSPOSED into Vt[d][row] with
// short4 stores (4 acc rows are contiguous in the transposed layout).
template <typename OT, int ROPE>
__global__ __launch_bounds__(256) void gemm_bt_lds(const short* __restrict__ A,
                                                   const short* __restrict__ Bm,
                                                   OT* __restrict__ C,
                                                   int M, int N, int K,
                                                   const float* __restrict__ cosb,
                                                   const float* __restrict__ sinb,
                                                   short* __restrict__ Vt) {
    __shared__ short As[128 * 32];
    __shared__ short Bs[128 * 32];

    int tid  = threadIdx.x;
    int wave = tid >> 6, lane = tid & 63;
    int quad = lane >> 4, l16 = lane & 15;
    int wm = wave >> 1, wn = wave & 1;

    // XCD swizzle (8 XCDs round-robin on default dispatch)
    int nwg  = gridDim.x * gridDim.y;
    int orig = blockIdx.y * gridDim.x + blockIdx.x;
    int wg   = orig;
    if ((nwg & 7) == 0) {
        int cpx = nwg >> 3;
        wg = (orig & 7) * cpx + (orig >> 3);
    }
    int bx = wg % gridDim.x, by = wg / gridDim.x;
    int m0 = by * 128, n0 = bx * 128;

    floatx4 acc[4][4];
    for (int i = 0; i < 4; i++)
        for (int j = 0; j < 4; j++) acc[i][j] = (floatx4){0.f, 0.f, 0.f, 0.f};

    int srow = lane >> 2;           // 0..15
    int skc  = (lane & 3) * 8;      // 0,8,16,24

    for (int k0 = 0; k0 < K; k0 += 32) {
        __syncthreads();
        for (int i = 0; i < 2; i++) {
            int r16 = wave * 32 + i * 16;
            load_lds16(A + (long)(m0 + r16 + srow) * K + k0 + skc, &As[r16 * 32]);
            load_lds16(Bm + (long)(n0 + r16 + srow) * K + k0 + skc, &Bs[r16 * 32]);
        }
        __syncthreads();

        short8 af[4], bfr[4];
        for (int i = 0; i < 4; i++)
            af[i] = *(const short8*)&As[(wm * 64 + i * 16 + l16) * 32 + quad * 8];
        for (int j = 0; j < 4; j++)
            bfr[j] = *(const short8*)&Bs[(wn * 64 + j * 16 + l16) * 32 + quad * 8];
        for (int i = 0; i < 4; i++)
            for (int j = 0; j < 4; j++)
                acc[i][j] = __builtin_amdgcn_mfma_f32_16x16x32_bf16(
                    af[i], bfr[j], acc[i][j], 0, 0, 0);
    }

    for (int j = 0; j < 4; j++) {
        int col = n0 + wn * 64 + j * 16 + l16;

        if constexpr (ROPE == 2) {
            if (col >= 512) {   // V half: transposed store Vt[d][row], short4
                int cv = col - 512;
                for (int i = 0; i < 4; i++) {
                    int row0 = m0 + wm * 64 + i * 16 + quad * 4;
                    short4 o;
                    o.x = f2bf(acc[i][j][0]);
                    o.y = f2bf(acc[i][j][1]);
                    o.z = f2bf(acc[i][j][2]);
                    o.w = f2bf(acc[i][j][3]);
                    *(short4*)&Vt[(long)cv * M + row0] = o;
                }
                continue;
            }
        }

        float c = 0.f, s = 0.f;
        bool rope_col = (ROPE == 1) || (ROPE == 2 && col < 512);
        if constexpr (ROPE != 0) {
            if (rope_col) {
                int hh = col >> 6;          // HEAD index (reference rope quirk)
                int ii = (col & 63) >> 1;   // pair index within head_dim
                c = cosb[hh * 32 + ii];
                s = sinb[hh * 32 + ii];
            }
        }
        for (int i = 0; i < 4; i++) {
            for (int r = 0; r < 4; r++) {
                int row = m0 + wm * 64 + i * 16 + quad * 4 + r;
                float v = acc[i][j][r];
                if constexpr (ROPE != 0) {
                    float p = __shfl_xor(v, 1);   // partner element of the pair
                    if (rope_col)
                        v = (col & 1) ? (p * s + v * c)    // o1 = t0*s + t1*c
                                      : (v * c - p * s);   // o0 = t0*c - t1*s
                }
                if constexpr (sizeof(OT) == 2)
                    C[(long)row * N + col] = f2bf(v);
                else
                    C[(long)row * N + col] = v;
            }
        }
    }
}

// Fused causal GQA flash attention — BARRIER-FREE + heavy-first.
// V comes pre-transposed (Vt[d][b*S+s]) from the KV GEMM epilogue, so PV
// B-fragments are direct contiguous 16B global loads (L2-resident) and no
// block-shared LDS staging exists. pT is wave-private (no __syncthreads in
// the whole kernel); every wave runs its own kv loop independently.
// Grid: (S/64, H, B); block 256 = 4 waves, each wave 16 q-rows; all waves of
// a block share the same causal tile count (uniform block runtime).
__global__ __launch_bounds__(256) void attn_kernel(const short* __restrict__ xq,
                                                   const short* __restrict__ xk,
                                                   const short* __restrict__ vt,
                                                   short* __restrict__ out,
                                                   int kvstride) {
    __shared__ short pT[4][16][72];   // per-wave P tile [row][key] (+pad)

    int qb = gridDim.x - 1 - blockIdx.x;   // heavy blocks first (tail balance)
    int h = blockIdx.y, b = blockIdx.z;
    int kvh = h >> 2;                 // GQA repeat_interleave: head h <- kv h/4
    int tid = threadIdx.x, wave = tid >> 6, lane = tid & 63;
    int quad = lane >> 4, l16 = lane & 15;

    int wr0  = qb * 64 + wave * 16;       // wave's first q-row
    int qrow = wr0 + l16;                 // A-fragment row (Q and P)
    int crow = wr0 + quad * 4;            // C-layout row base (+reg)

    // Q fragments for the whole kernel (HD=64 -> 2 k-steps)
    const short* qp = xq + (((long)b * kS + qrow) * kH + h) * kHD + quad * 8;
    short8 qf0 = *(const short8*)(qp);
    short8 qf1 = *(const short8*)(qp + 32);

    // all-ones bf16 B-fragment: mfma(P, ones) puts row-sum(P) in every column
    short8 ones;
    for (int i = 0; i < 8; i++) ones[i] = (short)0x3F80;

    float m_run[4];
    floatx4 acc_l = (floatx4){0.f, 0.f, 0.f, 0.f};   // online l per row
    floatx4 acc_o[4];
    for (int r = 0; r < 4; r++) m_run[r] = kNegBig;
    for (int nb = 0; nb < 4; nb++) acc_o[nb] = (floatx4){0.f, 0.f, 0.f, 0.f};

    const short* kbase0 = xk + (long)b * kS * kvstride + kvh * kHD;
    // Vt layout: [kvh*64 + d][b*kS + s], row stride kB*kS.
    const short* vbase = vt + (long)kvh * kHD * (kB * kS) + (long)b * kS;

    int nt = qb + 1;                  // causal: tiles 0..qb

    for (int kt = 0; kt < nt; kt++) {
        // K fragments: contiguous 16B per lane, L2-resident.
        short8 kf[4][2];
        const short* kbase = kbase0 + (long)kt * 64 * kvstride;
        for (int kb = 0; kb < 4; kb++) {
            const short* kp = kbase + (long)(kb * 16 + l16) * kvstride + quad * 8;
            kf[kb][0] = *(const short8*)kp;
            kf[kb][1] = *(const short8*)(kp + 32);
        }

        // Scores (raw, unscaled): Q(16xHD) x K^T(HDx64), 4 key-blocks.
        floatx4 accs[4];
        __builtin_amdgcn_s_setprio(1);
        for (int kb = 0; kb < 4; kb++) {
            accs[kb] = (floatx4){0.f, 0.f, 0.f, 0.f};
            accs[kb] = __builtin_amdgcn_mfma_f32_16x16x32_bf16(qf0, kf[kb][0], accs[kb], 0, 0, 0);
            accs[kb] = __builtin_amdgcn_mfma_f32_16x16x32_bf16(qf1, kf[kb][1], accs[kb], 0, 0, 0);
        }
        __builtin_amdgcn_s_setprio(0);

        float sv[4][4];   // [r][kb], raw scores
        for (int kb = 0; kb < 4; kb++)
            for (int r = 0; r < 4; r++) sv[r][kb] = accs[kb][r];

        if (kt == nt - 1) {  // causal mask: only the diagonal tile needs it
            for (int kb = 0; kb < 4; kb++)
                for (int r = 0; r < 4; r++) {
                    int kj = kt * 64 + kb * 16 + l16;
                    if (kj > crow + r) sv[r][kb] = kNegBig;
                }
        }

        // Online softmax with defer-max: exact 16-lane max per row; skip the
        // alpha-rescale entirely when no row's max grew by > kDeferThr (raw).
        float mx[4];
        for (int r = 0; r < 4; r++) {
            float m1 = fmaxf(fmaxf(sv[r][0], sv[r][1]), fmaxf(sv[r][2], sv[r][3]));
            for (int off = 1; off < 16; off <<= 1) m1 = fmaxf(m1, __shfl_xor(m1, off));
            mx[r] = m1;
        }
        bool small = (mx[0] - m_run[0] <= kDeferThr) && (mx[1] - m_run[1] <= kDeferThr) &&
                     (mx[2] - m_run[2] <= kDeferThr) && (mx[3] - m_run[3] <= kDeferThr);
        if (!__all(small)) {
            for (int r = 0; r < 4; r++) {
                float mnew = fmaxf(m_run[r], mx[r]);
                float alpha = exp2f((m_run[r] - mnew) * kC);
                m_run[r] = mnew;
                acc_l[r] *= alpha;
                for (int nb = 0; nb < 4; nb++) acc_o[nb][r] *= alpha;
            }
        }

        // P = 2^(sv*kC - m*kC)  (kC folded via fma; P <= 2^(kDeferThr*kC) ~ 147)
        for (int r = 0; r < 4; r++) {
            float mk = m_run[r] * kC;
            for (int kb = 0; kb < 4; kb++)
                sv[r][kb] = exp2f(fmaf(sv[r][kb], kC, -mk));
        }

        // P -> LDS (C-layout to A-layout transpose, wave-private, no barrier).
        for (int r = 0; r < 4; r++)
            for (int kb = 0; kb < 4; kb++)
                pT[wave][quad * 4 + r][kb * 16 + l16] = f2bf_fast(sv[r][kb]);

        // V fragments: issue early so L2 latency hides under the pT round-trip.
        // vf[nb][ks][j] = V[key = kt*64 + ks*32 + quad*8 + j][d = nb*16 + l16]
        short8 vf[4][2];
        for (int nb = 0; nb < 4; nb++) {
            const short* vp = vbase + (long)(nb * 16 + l16) * (kB * kS) + kt * 64 + quad * 8;
            vf[nb][0] = *(const short8*)(vp);
            vf[nb][1] = *(const short8*)(vp + 32);
        }

        // PV + row-sum: P(16x64) x [V(64xHD) | ones]
        short8 pf0 = *(const short8*)&pT[wave][l16][quad * 8];
        short8 pf1 = *(const short8*)&pT[wave][l16][32 + quad * 8];
        __builtin_amdgcn_s_setprio(1);
        acc_l = __builtin_amdgcn_mfma_f32_16x16x32_bf16(pf0, ones, acc_l, 0, 0, 0);
        acc_l = __builtin_amdgcn_mfma_f32_16x16x32_bf16(pf1, ones, acc_l, 0, 0, 0);
        for (int nb = 0; nb < 4; nb++) {
            acc_o[nb] = __builtin_amdgcn_mfma_f32_16x16x32_bf16(pf0, vf[nb][0], acc_o[nb], 0, 0, 0);
            acc_o[nb] = __builtin_amdgcn_mfma_f32_16x16x32_bf16(pf1, vf[nb][1], acc_o[nb], 0, 0, 0);
        }
        __builtin_amdgcn_s_setprio(0);
    }

    // Epilogue: normalize and store (B,S,H,HD) bf16.
    for (int r = 0; r < 4; r++) {
        float inv = 1.0f / fmaxf(acc_l[r], 1e-20f);
        int row = crow + r;
        for (int nb = 0; nb < 4; nb++)
            out[(((long)b * kS + row) * kH + h) * kHD + nb * 16 + l16] =
                f2bf(acc_o[nb][r] * inv);
    }
}

extern "C" void kernel_launch(void* const* d_in, const int* in_sizes, int n_in,
                              void* d_out, int out_size, void* d_ws, size_t ws_size,
                              hipStream_t stream) {
    // setup_inputs order: x, freqs_cos, freqs_sin, mask, wq, wk, wv, wo
    const float* x  = (const float*)d_in[0];
    const float* fc = (const float*)d_in[1];
    const float* fs = (const float*)d_in[2];
    // d_in[3] = mask: structurally causal, implemented structurally.
    const float* wq = (const float*)d_in[4];
    const float* wk = (const float*)d_in[5];
    const float* wv = (const float*)d_in[6];
    const float* wo = (const float*)d_in[7];

    const int M = kB * kS;                // 4096
    const long MB = 1l << 20;

    // ws (peak 24 MiB, stream-ordered):   d_out (32 MiB):
    //   [ 0,16) xb   — dead after KV-proj   [ 0,16) xq bf16 (M x 2048)
    //   [16,24) wqb  — dead after Q-proj    [16,24) xkv bf16 (M x 1024: K|junk)
    //   [16,20) wkvb (over wqb)             [24,28) vt bf16 (512 x M, transposed V)
    //   [ 0,16) ao   (over xb)              final: 32 MiB fp32 out (after attn)
    //   [16,24) wob  (over wkvb)
    char* ws = (char*)d_ws;
    short* xb   = (short*)(ws);
    short* wqb  = (short*)(ws + 16 * MB);
    short* wkvb = (short*)(ws + 16 * MB);
    short* ao   = (short*)(ws);
    short* wob  = (short*)(ws + 16 * MB);
    char*  dob  = (char*)d_out;
    short* xq   = (short*)(dob);
    short* xkv  = (short*)(dob + 16 * MB);
    short* vt   = (short*)(dob + 24 * MB);

    const int nX  = M * kD;         // 8388608
    const int nWq = kD * kD;        // 4194304
    const int nWk = kKV * kHD * kD; // 1048576

    cast_f2b<<<(nX / 4 + 255) / 256, 256, 0, stream>>>(x, xb, nX / 4);
    cast_f2b<<<(nWq / 4 + 255) / 256, 256, 0, stream>>>(wq, wqb, nWq / 4);
    // Q projection with fused RoPE (all 2048 columns, head-indexed tables).
    gemm_bt_lds<short, 1><<<dim3(kD / 128, M / 128), 256, 0, stream>>>(
        xb, wqb, xq, M, kD, kD, fc, fs, nullptr);

    // Fused KV weights: rows 0..511 = wk, rows 512..1023 = wv.
    cast_f2b<<<(nWk / 4 + 255) / 256, 256, 0, stream>>>(wk, wkvb, nWk / 4);
    cast_f2b<<<(nWk / 4 + 255) / 256, 256, 0, stream>>>(wv, wkvb + nWk, nWk / 4);
    // KV projection: RoPE on K cols (<512), V cols stored transposed into vt.
    gemm_bt_lds<short, 2><<<dim3(1024 / 128, M / 128), 256, 0, stream>>>(
        xb, wkvb, xkv, M, 1024, kD, fc, fs, vt);

    attn_kernel<<<dim3(kS / 64, kH, kB), 256, 0, stream>>>(
        xq, xkv, vt, ao, 1024);

    cast_f2b<<<(nWq / 4 + 255) / 256, 256, 0, stream>>>(wo, wob, nWq / 4);
    gemm_bt_lds<float, 0><<<dim3(kD / 128, M / 128), 256, 0, stream>>>(
        ao, wob, (float*)d_out, M, kD, kD, nullptr, nullptr, nullptr);
}

// Round 6
// 412.190 us; speedup vs baseline: 1.2452x; 1.2452x over previous
//
#include <hip/hip_runtime.h>
#include <hip/hip_bf16.h>

// Problem constants
constexpr int kB  = 4;
constexpr int kS  = 1024;
constexpr int kD  = 2048;
constexpr int kH  = 32;
constexpr int kKV = 8;
constexpr int kHD = 64;
constexpr int kM  = kB * kS;    // 4096
constexpr int kNT = kS / 64;    // 16 kv tiles

constexpr float kNegBig = -30000.0f;   // finite sentinel: no inf/overflow paths
constexpr float kC = 0.125f * 1.44269504f;  // 1/sqrt(HD) folded into exp2
constexpr float kDeferThr = 40.0f;     // defer-max raw threshold: P <= 2^(40*kC) ~ 147

typedef __attribute__((ext_vector_type(8))) short short8;   // 8 bf16 (4 VGPRs)
typedef __attribute__((ext_vector_type(4))) float floatx4;  // MFMA C/D

static __device__ __forceinline__ float bf2f(short v) {
    unsigned int u = ((unsigned int)(unsigned short)v) << 16;
    return __builtin_bit_cast(float, u);
}
static __device__ __forceinline__ short f2bf(float f) {
    unsigned int u = __builtin_bit_cast(unsigned int, f);
    unsigned int lsb = (u >> 16) & 1u;
    u += 0x7fffu + lsb;                       // round-to-nearest-even
    return (short)(u >> 16);
}
// Cheap pack for P >= 0: round-half-up (bias ~2^-9 relative, harmless).
static __device__ __forceinline__ short f2bf_fast(float f) {
    unsigned int u = __builtin_bit_cast(unsigned int, f);
    return (short)((u + 0x8000u) >> 16);
}

// Async global->LDS, 16 B per lane. LDS dest is wave-uniform base + lane*16.
static __device__ __forceinline__ void load_lds16(const short* g, short* l) {
    __builtin_amdgcn_global_load_lds(
        (const __attribute__((address_space(1))) unsigned int*)g,
        (__attribute__((address_space(3))) unsigned int*)l, 16, 0, 0);
}

// fp32 -> bf16, vectorized x4. n4 = element_count/4.
__global__ void cast_f2b(const float* __restrict__ in, short* __restrict__ outp, int n4) {
    int gid = blockIdx.x * blockDim.x + threadIdx.x;
    if (gid >= n4) return;
    float4 v = ((const float4*)in)[gid];
    short4 o;
    o.x = f2bf(v.x); o.y = f2bf(v.y); o.z = f2bf(v.z); o.w = f2bf(v.w);
    ((short4*)outp)[gid] = o;
}

// C[M,N] = A[M,K] * B[N,K]^T, bf16 in, fp32 acc, OT out (bf16 short or fp32).
// m97 structure: 128x128 tile, BK=32, global_load_lds width=16 staging,
// 2-barrier K-loop, ds_read_b128 fragments. Block = 4 waves in 2x2.
// XCD-aware bijective blockIdx swizzle (T1); requires nwg % 8 == 0 (guarded).
// ROPE: 0 = none, 1 = all columns (Q proj), 2 = KV mode: cols < 512 get RoPE
// (K half), cols >= 512 (V half) are stored TRANSPOSED into Vt[d][row] with
// short4 stores (4 acc rows are contiguous in the transposed layout).
template <typename OT, int ROPE>
__global__ __launch_bounds__(256) void gemm_bt_lds(const short* __restrict__ A,
                                                   const short* __restrict__ Bm,
                                                   OT* __restrict__ C,
                                                   int M, int N, int K,
                                                   const float* __restrict__ cosb,
                                                   const float* __restrict__ sinb,
                                                   short* __restrict__ Vt) {
    __shared__ short As[128 * 32];
    __shared__ short Bs[128 * 32];

    int tid  = threadIdx.x;
    int wave = tid >> 6, lane = tid & 63;
    int quad = lane >> 4, l16 = lane & 15;
    int wm = wave >> 1, wn = wave & 1;

    // XCD swizzle (8 XCDs round-robin on default dispatch)
    int nwg  = gridDim.x * gridDim.y;
    int orig = blockIdx.y * gridDim.x + blockIdx.x;
    int wg   = orig;
    if ((nwg & 7) == 0) {
        int cpx = nwg >> 3;
        wg = (orig & 7) * cpx + (orig >> 3);
    }
    int bx = wg % gridDim.x, by = wg / gridDim.x;
    int m0 = by * 128, n0 = bx * 128;

    floatx4 acc[4][4];
    for (int i = 0; i < 4; i++)
        for (int j = 0; j < 4; j++) acc[i][j] = (floatx4){0.f, 0.f, 0.f, 0.f};

    int srow = lane >> 2;           // 0..15
    int skc  = (lane & 3) * 8;      // 0,8,16,24

    for (int k0 = 0; k0 < K; k0 += 32) {
        __syncthreads();
        for (int i = 0; i < 2; i++) {
            int r16 = wave * 32 + i * 16;
            load_lds16(A + (long)(m0 + r16 + srow) * K + k0 + skc, &As[r16 * 32]);
            load_lds16(Bm + (long)(n0 + r16 + srow) * K + k0 + skc, &Bs[r16 * 32]);
        }
        __syncthreads();

        short8 af[4], bfr[4];
        for (int i = 0; i < 4; i++)
            af[i] = *(const short8*)&As[(wm * 64 + i * 16 + l16) * 32 + quad * 8];
        for (int j = 0; j < 4; j++)
            bfr[j] = *(const short8*)&Bs[(wn * 64 + j * 16 + l16) * 32 + quad * 8];
        for (int i = 0; i < 4; i++)
            for (int j = 0; j < 4; j++)
                acc[i][j] = __builtin_amdgcn_mfma_f32_16x16x32_bf16(
                    af[i], bfr[j], acc[i][j], 0, 0, 0);
    }

    for (int j = 0; j < 4; j++) {
        int col = n0 + wn * 64 + j * 16 + l16;

        if constexpr (ROPE == 2) {
            if (col >= 512) {   // V half: transposed store Vt[d][row], short4
                int cv = col - 512;
                for (int i = 0; i < 4; i++) {
                    int row0 = m0 + wm * 64 + i * 16 + quad * 4;
                    short4 o;
                    o.x = f2bf(acc[i][j][0]);
                    o.y = f2bf(acc[i][j][1]);
                    o.z = f2bf(acc[i][j][2]);
                    o.w = f2bf(acc[i][j][3]);
                    *(short4*)&Vt[(long)cv * M + row0] = o;
                }
                continue;
            }
        }

        float c = 0.f, s = 0.f;
        bool rope_col = (ROPE == 1) || (ROPE == 2 && col < 512);
        if constexpr (ROPE != 0) {
            if (rope_col) {
                int hh = col >> 6;          // HEAD index (reference rope quirk)
                int ii = (col & 63) >> 1;   // pair index within head_dim
                c = cosb[hh * 32 + ii];
                s = sinb[hh * 32 + ii];
            }
        }
        for (int i = 0; i < 4; i++) {
            for (int r = 0; r < 4; r++) {
                int row = m0 + wm * 64 + i * 16 + quad * 4 + r;
                float v = acc[i][j][r];
                if constexpr (ROPE != 0) {
                    float p = __shfl_xor(v, 1);   // partner element of the pair
                    if (rope_col)
                        v = (col & 1) ? (p * s + v * c)    // o1 = t0*s + t1*c
                                      : (v * c - p * s);   // o0 = t0*c - t1*s
                }
                if constexpr (sizeof(OT) == 2)
                    C[(long)row * N + col] = f2bf(v);
                else
                    C[(long)row * N + col] = v;
            }
        }
    }
}

// Fused causal GQA flash attention — Round-12: latency-attack version.
// Diagnosis from round-5 counters: ~14K cyc/kv-iter of EXPOSED global-load
// latency (MfmaUtil 3.4%, VALU 16%, HBM 2.7%, occ 20%) + decay-tail imbalance.
// Fixes: (a) register double-buffer PREFETCH of K (t+1 issued before tile t's
// compute), V issued right after QK so softmax covers it; (b) uniform work
// pairing: block pb handles q-tiles {15-pb, pb} = 17 kv-iters for every block
// (no tail). Barrier-free structure retained (pT wave-private).
// Grid: (S/128, H, B); block 256 = 4 waves.
__global__ __launch_bounds__(256) void attn_kernel(const short* __restrict__ xq,
                                                   const short* __restrict__ xk,
                                                   const short* __restrict__ vt,
                                                   short* __restrict__ out,
                                                   int kvstride) {
    __shared__ short pT[4][16][72];   // per-wave P tile [row][key] (+pad)

    int pb = blockIdx.x;              // 0..7: handles q-tiles {15-pb, pb}
    int h = blockIdx.y, b = blockIdx.z;
    int kvh = h >> 2;                 // GQA repeat_interleave: head h <- kv h/4
    int tid = threadIdx.x, wave = tid >> 6, lane = tid & 63;
    int quad = lane >> 4, l16 = lane & 15;

    const short* kbase0 = xk + (long)b * kS * kvstride + kvh * kHD;
    // Vt layout: [kvh*64 + d][b*kS + s], row stride kM.
    const short* vbase = vt + (long)kvh * kHD * kM + (long)b * kS;

    // all-ones bf16 B-fragment: mfma(P, ones) puts row-sum(P) in every column
    short8 ones;
    for (int i = 0; i < 8; i++) ones[i] = (short)0x3F80;

    auto loadK = [&](short8 (&kf)[4][2], int kt) {
        const short* kbase = kbase0 + (long)kt * 64 * kvstride;
        for (int kb = 0; kb < 4; kb++) {
            const short* kp = kbase + (long)(kb * 16 + l16) * kvstride + quad * 8;
            kf[kb][0] = *(const short8*)kp;
            kf[kb][1] = *(const short8*)(kp + 32);
        }
    };

    for (int qi = 0; qi < 2; qi++) {
        int qb = (qi == 0) ? (kNT - 1 - pb) : pb;   // heavy tile first
        int nt = qb + 1;
        int wr0  = qb * 64 + wave * 16;
        int qrow = wr0 + l16;
        int crow = wr0 + quad * 4;

        const short* qp = xq + (((long)b * kS + qrow) * kH + h) * kHD + quad * 8;
        short8 qf0 = *(const short8*)(qp);
        short8 qf1 = *(const short8*)(qp + 32);

        float m_run[4];
        floatx4 acc_l = (floatx4){0.f, 0.f, 0.f, 0.f};
        floatx4 acc_o[4];
        for (int r = 0; r < 4; r++) m_run[r] = kNegBig;
        for (int nb = 0; nb < 4; nb++) acc_o[nb] = (floatx4){0.f, 0.f, 0.f, 0.f};

        auto step = [&](short8 (&kf)[4][2], int kt) {
            // Scores (raw): Q(16xHD) x K^T(HDx64), 4 key-blocks, acc in-place.
            floatx4 accs[4];
            __builtin_amdgcn_s_setprio(1);
            for (int kb = 0; kb < 4; kb++) {
                accs[kb] = (floatx4){0.f, 0.f, 0.f, 0.f};
                accs[kb] = __builtin_amdgcn_mfma_f32_16x16x32_bf16(qf0, kf[kb][0], accs[kb], 0, 0, 0);
                accs[kb] = __builtin_amdgcn_mfma_f32_16x16x32_bf16(qf1, kf[kb][1], accs[kb], 0, 0, 0);
            }
            __builtin_amdgcn_s_setprio(0);

            // V fragments: issue NOW — the whole softmax below covers the
            // latency. vf[nb][ks][j] = V[key=kt*64+ks*32+quad*8+j][d=nb*16+l16]
            short8 vf[4][2];
            for (int nb = 0; nb < 4; nb++) {
                const short* vp = vbase + (long)(nb * 16 + l16) * kM + kt * 64 + quad * 8;
                vf[nb][0] = *(const short8*)(vp);
                vf[nb][1] = *(const short8*)(vp + 32);
            }

            if (kt == nt - 1) {  // causal mask: only the diagonal tile
                for (int kb = 0; kb < 4; kb++)
                    for (int r = 0; r < 4; r++) {
                        int kj = kt * 64 + kb * 16 + l16;
                        if (kj > crow + r) accs[kb][r] = kNegBig;
                    }
            }

            // Online softmax with defer-max (16-lane exact max per row).
            float mx[4];
            for (int r = 0; r < 4; r++) {
                float m1 = fmaxf(fmaxf(accs[0][r], accs[1][r]),
                                 fmaxf(accs[2][r], accs[3][r]));
                for (int off = 1; off < 16; off <<= 1) m1 = fmaxf(m1, __shfl_xor(m1, off));
                mx[r] = m1;
            }
            bool small = (mx[0] - m_run[0] <= kDeferThr) && (mx[1] - m_run[1] <= kDeferThr) &&
                         (mx[2] - m_run[2] <= kDeferThr) && (mx[3] - m_run[3] <= kDeferThr);
            if (!__all(small)) {
                for (int r = 0; r < 4; r++) {
                    float mnew = fmaxf(m_run[r], mx[r]);
                    float alpha = exp2f((m_run[r] - mnew) * kC);
                    m_run[r] = mnew;
                    acc_l[r] *= alpha;
                    for (int nb = 0; nb < 4; nb++) acc_o[nb][r] *= alpha;
                }
            }

            // P = 2^(s*kC - m*kC); P <= 2^(kDeferThr*kC) ~ 147 (bf16-safe).
            for (int r = 0; r < 4; r++) {
                float mk = m_run[r] * kC;
                for (int kb = 0; kb < 4; kb++)
                    accs[kb][r] = exp2f(fmaf(accs[kb][r], kC, -mk));
            }

            // P -> LDS (C-layout to A-layout transpose, wave-private).
            for (int r = 0; r < 4; r++)
                for (int kb = 0; kb < 4; kb++)
                    pT[wave][quad * 4 + r][kb * 16 + l16] = f2bf_fast(accs[kb][r]);

            // PV + row-sum: P(16x64) x [V(64xHD) | ones]
            short8 pf0 = *(const short8*)&pT[wave][l16][quad * 8];
            short8 pf1 = *(const short8*)&pT[wave][l16][32 + quad * 8];
            __builtin_amdgcn_s_setprio(1);
            acc_l = __builtin_amdgcn_mfma_f32_16x16x32_bf16(pf0, ones, acc_l, 0, 0, 0);
            acc_l = __builtin_amdgcn_mfma_f32_16x16x32_bf16(pf1, ones, acc_l, 0, 0, 0);
            for (int nb = 0; nb < 4; nb++) {
                acc_o[nb] = __builtin_amdgcn_mfma_f32_16x16x32_bf16(pf0, vf[nb][0], acc_o[nb], 0, 0, 0);
                acc_o[nb] = __builtin_amdgcn_mfma_f32_16x16x32_bf16(pf1, vf[nb][1], acc_o[nb], 0, 0, 0);
            }
            __builtin_amdgcn_s_setprio(0);
        };

        // K register double-buffer: load t+1 BEFORE computing t.
        short8 kfA[4][2], kfB[4][2];
        loadK(kfA, 0);
        int kt = 0;
        while (true) {
            if (kt + 1 < nt) loadK(kfB, kt + 1);
            step(kfA, kt);
            if (++kt >= nt) break;
            if (kt + 1 < nt) loadK(kfA, kt + 1);
            step(kfB, kt);
            if (++kt >= nt) break;
        }

        // Epilogue: normalize and store (B,S,H,HD) bf16.
        for (int r = 0; r < 4; r++) {
            float inv = 1.0f / fmaxf(acc_l[r], 1e-20f);
            int row = crow + r;
            for (int nb = 0; nb < 4; nb++)
                out[(((long)b * kS + row) * kH + h) * kHD + nb * 16 + l16] =
                    f2bf(acc_o[nb][r] * inv);
        }
    }
}

extern "C" void kernel_launch(void* const* d_in, const int* in_sizes, int n_in,
                              void* d_out, int out_size, void* d_ws, size_t ws_size,
                              hipStream_t stream) {
    // setup_inputs order: x, freqs_cos, freqs_sin, mask, wq, wk, wv, wo
    const float* x  = (const float*)d_in[0];
    const float* fc = (const float*)d_in[1];
    const float* fs = (const float*)d_in[2];
    // d_in[3] = mask: structurally causal, implemented structurally.
    const float* wq = (const float*)d_in[4];
    const float* wk = (const float*)d_in[5];
    const float* wv = (const float*)d_in[6];
    const float* wo = (const float*)d_in[7];

    const int M = kM;                     // 4096
    const long MB = 1l << 20;

    // ws (peak 24 MiB, stream-ordered):   d_out (32 MiB):
    //   [ 0,16) xb   — dead after KV-proj   [ 0,16) xq bf16 (M x 2048)
    //   [16,24) wqb  — dead after Q-proj    [16,24) xkv bf16 (M x 1024: K|junk)
    //   [16,20) wkvb (over wqb)             [24,28) vt bf16 (512 x M, transposed V)
    //   [ 0,16) ao   (over xb)              final: 32 MiB fp32 out (after attn)
    //   [16,24) wob  (over wkvb)
    char* ws = (char*)d_ws;
    short* xb   = (short*)(ws);
    short* wqb  = (short*)(ws + 16 * MB);
    short* wkvb = (short*)(ws + 16 * MB);
    short* ao   = (short*)(ws);
    short* wob  = (short*)(ws + 16 * MB);
    char*  dob  = (char*)d_out;
    short* xq   = (short*)(dob);
    short* xkv  = (short*)(dob + 16 * MB);
    short* vt   = (short*)(dob + 24 * MB);

    const int nX  = M * kD;         // 8388608
    const int nWq = kD * kD;        // 4194304
    const int nWk = kKV * kHD * kD; // 1048576

    cast_f2b<<<(nX / 4 + 255) / 256, 256, 0, stream>>>(x, xb, nX / 4);
    cast_f2b<<<(nWq / 4 + 255) / 256, 256, 0, stream>>>(wq, wqb, nWq / 4);
    // Q projection with fused RoPE (all 2048 columns, head-indexed tables).
    gemm_bt_lds<short, 1><<<dim3(kD / 128, M / 128), 256, 0, stream>>>(
        xb, wqb, xq, M, kD, kD, fc, fs, nullptr);

    // Fused KV weights: rows 0..511 = wk, rows 512..1023 = wv.
    cast_f2b<<<(nWk / 4 + 255) / 256, 256, 0, stream>>>(wk, wkvb, nWk / 4);
    cast_f2b<<<(nWk / 4 + 255) / 256, 256, 0, stream>>>(wv, wkvb + nWk, nWk / 4);
    // KV projection: RoPE on K cols (<512), V cols stored transposed into vt.
    gemm_bt_lds<short, 2><<<dim3(1024 / 128, M / 128), 256, 0, stream>>>(
        xb, wkvb, xkv, M, 1024, kD, fc, fs, vt);

    attn_kernel<<<dim3(kS / 128, kH, kB), 256, 0, stream>>>(
        xq, xkv, vt, ao, 1024);

    cast_f2b<<<(nWq / 4 + 255) / 256, 256, 0, stream>>>(wo, wob, nWq / 4);
    gemm_bt_lds<float, 0><<<dim3(kD / 128, M / 128), 256, 0, stream>>>(
        ao, wob, (float*)d_out, M, kD, kD, nullptr, nullptr, nullptr);
}